// Round 1
// baseline (736.271 us; speedup 1.0000x reference)
//
#include <hip/hip_runtime.h>
#include <hip/hip_bf16.h>

// ---------------- problem constants ----------------
#define BB     2
#define NN     2065          // N_PATCH + N_TABLE + N_CLS
#define NPAD   2112          // 33*64
#define HH     8
#define DD     64
#define EE     512
#define MROWS  (BB*NN)       // 4130
#define NPATCH 2048
#define NTAB   16
#define SCALEF 0.125f
#define EPSF   1e-6f

typedef __bf16 bf16;
typedef bf16  bf16x8 __attribute__((ext_vector_type(8)));
typedef bf16  bf16x4v __attribute__((ext_vector_type(4)));
typedef float f32x4  __attribute__((ext_vector_type(4)));

#define LDS_STRIDE 72   // 64 + 8 pad bf16 (144 B rows, 16B aligned)

// ---------------- prep kernels ----------------
__global__ __launch_bounds__(256) void k_zero(uint4* __restrict__ p, int n4) {
    int i = blockIdx.x * 256 + threadIdx.x;
    if (i < n4) { uint4 z = {0,0,0,0}; p[i] = z; }
}

__global__ __launch_bounds__(256) void k_cvt(const float* __restrict__ x,
                                             bf16* __restrict__ o, int n4) {
    int i = blockIdx.x * 256 + threadIdx.x;
    if (i < n4) {
        float4 v = ((const float4*)x)[i];
        bf16x4v r;
        r[0] = (bf16)v.x; r[1] = (bf16)v.y; r[2] = (bf16)v.z; r[3] = (bf16)v.w;
        *(bf16x4v*)(o + 4*(size_t)i) = r;
    }
}

// out[c*512 + k] = in[k*C + c]   (weights have 512 rows)
__global__ __launch_bounds__(256) void k_transcvt(const float* __restrict__ w,
                                                  bf16* __restrict__ o,
                                                  int C, int total) {
    int i = blockIdx.x * 256 + threadIdx.x;
    if (i < total) {
        int k = i & 511, c = i >> 9;
        o[i] = (bf16)w[(size_t)k * C + c];
    }
}

// ---------------- GEMM1: qkv = x @ w_qkv + b ; scatter into Qh/Kh/Vt ----------------
__global__ __launch_bounds__(256) void k_gemm_qkv(
    const bf16* __restrict__ xb, const bf16* __restrict__ wt,
    const float* __restrict__ bias,
    bf16* __restrict__ Qh, bf16* __restrict__ Kh, bf16* __restrict__ Vt)
{
    __shared__ bf16 As[64][LDS_STRIDE];
    __shared__ bf16 Bs[64][LDS_STRIDE];
    int t = threadIdx.x;
    int w = t >> 6, l = t & 63, l15 = l & 15, quad = l >> 4;
    int m0 = blockIdx.y * 64, c0 = blockIdx.x * 64;
    int srow = t >> 2, sseg = (t & 3) * 16;
    f32x4 acc[4] = {};

    for (int kk = 0; kk < 512; kk += 64) {
        {
            int m = m0 + srow;
            uint4 v0 = {0,0,0,0}, v1 = {0,0,0,0};
            if (m < MROWS) {
                const uint4* src = (const uint4*)(xb + (size_t)m*512 + kk + sseg);
                v0 = src[0]; v1 = src[1];
            }
            *(uint4*)&As[srow][sseg]     = v0;
            *(uint4*)&As[srow][sseg + 8] = v1;
            const uint4* bs = (const uint4*)(wt + (size_t)(c0 + srow)*512 + kk + sseg);
            *(uint4*)&Bs[srow][sseg]     = bs[0];
            *(uint4*)&Bs[srow][sseg + 8] = bs[1];
        }
        __syncthreads();
        #pragma unroll
        for (int kh = 0; kh < 2; kh++) {
            bf16x8 a = *(const bf16x8*)&As[w*16 + l15][kh*32 + quad*8];
            #pragma unroll
            for (int c = 0; c < 4; c++) {
                bf16x8 b = *(const bf16x8*)&Bs[c*16 + l15][kh*32 + quad*8];
                acc[c] = __builtin_amdgcn_mfma_f32_16x16x32_bf16(a, b, acc[c], 0, 0, 0);
            }
        }
        __syncthreads();
    }

    int which = c0 >> 9;             // 0=q 1=k 2=v (uniform per block)
    int h = (c0 & 511) >> 6;         // uniform per block
    #pragma unroll
    for (int c = 0; c < 4; c++) {
        int d  = (c0 & 63) + c*16 + l15;   // c0 is mult of 64 -> d = c*16+l15
        float bv = bias[c0 + c*16 + l15];
        #pragma unroll
        for (int r = 0; r < 4; r++) {
            int m = m0 + w*16 + quad*4 + r;
            if (m >= MROWS) continue;
            int b_ = m / NN, n = m - b_ * NN;
            int bh = b_ * 8 + h;
            float v = acc[c][r] + bv;
            if (which == 0)      Qh[(size_t)(bh*NPAD + n)*64 + d] = (bf16)v;
            else if (which == 1) Kh[(size_t)(bh*NPAD + n)*64 + d] = (bf16)v;
            else                 Vt[((size_t)bh*64 + d)*NPAD + n] = (bf16)v;
        }
    }
}

// ---------------- attention pass 1: A_raw + per-row coefficients ----------------
__global__ __launch_bounds__(256) void k_attn1(
    const bf16* __restrict__ Qh, const bf16* __restrict__ Kh,
    float* __restrict__ Araw, float4* __restrict__ stats)
{
    __shared__ bf16 Qs[64][LDS_STRIDE];
    __shared__ bf16 Ks[64][LDS_STRIDE];
    int t = threadIdx.x;
    int w = t >> 6, l = t & 63, l15 = l & 15, quad = l >> 4;
    int n0 = blockIdx.x * 64;
    int bh = blockIdx.y;
    int srow = t >> 2, sseg = (t & 3) * 16;
    {
        const uint4* src = (const uint4*)(Qh + (size_t)(bh*NPAD + n0 + srow)*64 + sseg);
        *(uint4*)&Qs[srow][sseg]     = src[0];
        *(uint4*)&Qs[srow][sseg + 8] = src[1];
    }
    float sp[4]  = {0,0,0,0}, sep[4] = {0,0,0,0};
    float st[4]  = {0,0,0,0}, set_[4] = {0,0,0,0}, cv[4] = {0,0,0,0};
    int nrow[4];
    #pragma unroll
    for (int r = 0; r < 4; r++) nrow[r] = n0 + w*16 + quad*4 + r;

    for (int kt = 0; kt < 33; kt++) {
        __syncthreads();
        {
            const uint4* src = (const uint4*)(Kh + (size_t)(bh*NPAD + kt*64 + srow)*64 + sseg);
            *(uint4*)&Ks[srow][sseg]     = src[0];
            *(uint4*)&Ks[srow][sseg + 8] = src[1];
        }
        __syncthreads();
        f32x4 acc[4] = {};
        #pragma unroll
        for (int kh = 0; kh < 2; kh++) {
            bf16x8 a = *(const bf16x8*)&Qs[w*16 + l15][kh*32 + quad*8];
            #pragma unroll
            for (int c = 0; c < 4; c++) {
                bf16x8 b = *(const bf16x8*)&Ks[c*16 + l15][kh*32 + quad*8];
                acc[c] = __builtin_amdgcn_mfma_f32_16x16x32_bf16(a, b, acc[c], 0, 0, 0);
            }
        }
        #pragma unroll
        for (int c = 0; c < 4; c++) {
            int col = kt*64 + c*16 + l15;
            #pragma unroll
            for (int r = 0; r < 4; r++) {
                float val = acc[c][r] * SCALEF;
                float e = __expf(val);
                if (col < NPATCH)            { sp[r] += val; sep[r] += e; }
                else if (col < NPATCH+NTAB)  { st[r] += val; set_[r] += e; }
                else if (col == NPATCH+NTAB) { cv[r] = val; }
                if (col < NN && nrow[r] < NN)
                    Araw[((size_t)(bh*NN + nrow[r]))*NN + col] = val;
            }
        }
    }
    #pragma unroll
    for (int r = 0; r < 4; r++) {
        #pragma unroll
        for (int m = 1; m < 16; m <<= 1) {
            sp[r]   += __shfl_xor(sp[r],   m, 64);
            sep[r]  += __shfl_xor(sep[r],  m, 64);
            st[r]   += __shfl_xor(st[r],   m, 64);
            set_[r] += __shfl_xor(set_[r], m, 64);
            cv[r]   += __shfl_xor(cv[r],   m, 64);
        }
    }
    if (l15 == 0) {
        #pragma unroll
        for (int r = 0; r < 4; r++) {
            if (nrow[r] < NN) {
                float ep = __expf(sp[r] * (1.0f / NPATCH));
                float et = __expf(st[r] * (1.0f / NTAB));
                float ec = __expf(cv[r]);
                float s  = ep + et + ec;
                float4 o;
                o.x = ep / (s * (sep[r]  + EPSF));
                o.y = et / (s * (set_[r] + EPSF));
                o.z = ec / (s * (ec      + EPSF));
                o.w = 0.f;
                stats[bh*NPAD + nrow[r]] = o;
            }
        }
    }
}

// ---------------- attention pass 2: A + context ----------------
__global__ __launch_bounds__(256) void k_attn2(
    const bf16* __restrict__ Qh, const bf16* __restrict__ Kh,
    const bf16* __restrict__ Vt, const float4* __restrict__ stats,
    float* __restrict__ A, bf16* __restrict__ attn)
{
    __shared__ bf16 Qs[64][LDS_STRIDE];
    __shared__ bf16 Ks[64][LDS_STRIDE];
    __shared__ bf16 Vs[64][LDS_STRIDE];
    __shared__ bf16 Ps[64][LDS_STRIDE];
    int t = threadIdx.x;
    int w = t >> 6, l = t & 63, l15 = l & 15, quad = l >> 4;
    int n0 = blockIdx.x * 64;
    int bh = blockIdx.y;
    int srow = t >> 2, sseg = (t & 3) * 16;
    {
        const uint4* src = (const uint4*)(Qh + (size_t)(bh*NPAD + n0 + srow)*64 + sseg);
        *(uint4*)&Qs[srow][sseg]     = src[0];
        *(uint4*)&Qs[srow][sseg + 8] = src[1];
    }
    int nrow[4];
    float cp[4], ctb[4], cc[4];
    #pragma unroll
    for (int r = 0; r < 4; r++) {
        nrow[r] = n0 + w*16 + quad*4 + r;
        float4 s4 = stats[bh*NPAD + nrow[r]];
        cp[r] = s4.x; ctb[r] = s4.y; cc[r] = s4.z;
    }
    f32x4 o[4] = {};

    for (int kt = 0; kt < 33; kt++) {
        __syncthreads();
        {
            const uint4* ks = (const uint4*)(Kh + (size_t)(bh*NPAD + kt*64 + srow)*64 + sseg);
            *(uint4*)&Ks[srow][sseg]     = ks[0];
            *(uint4*)&Ks[srow][sseg + 8] = ks[1];
            const uint4* vs = (const uint4*)(Vt + ((size_t)bh*64 + srow)*NPAD + kt*64 + sseg);
            *(uint4*)&Vs[srow][sseg]     = vs[0];
            *(uint4*)&Vs[srow][sseg + 8] = vs[1];
        }
        __syncthreads();
        f32x4 acc[4] = {};
        #pragma unroll
        for (int kh = 0; kh < 2; kh++) {
            bf16x8 a = *(const bf16x8*)&Qs[w*16 + l15][kh*32 + quad*8];
            #pragma unroll
            for (int c = 0; c < 4; c++) {
                bf16x8 b = *(const bf16x8*)&Ks[c*16 + l15][kh*32 + quad*8];
                acc[c] = __builtin_amdgcn_mfma_f32_16x16x32_bf16(a, b, acc[c], 0, 0, 0);
            }
        }
        #pragma unroll
        for (int c = 0; c < 4; c++) {
            int col = kt*64 + c*16 + l15;
            #pragma unroll
            for (int r = 0; r < 4; r++) {
                float val = acc[c][r] * SCALEF;
                float e = __expf(val);
                float coef = (col < NPATCH) ? cp[r]
                           : (col < NPATCH+NTAB) ? ctb[r]
                           : (col == NPATCH+NTAB) ? cc[r] : 0.f;
                float av = e * coef;
                if (col < NN && nrow[r] < NN)
                    A[((size_t)(bh*NN + nrow[r]))*NN + col] = av;
                Ps[w*16 + quad*4 + r][c*16 + l15] = (bf16)av;
            }
        }
        __syncthreads();
        #pragma unroll
        for (int kh = 0; kh < 2; kh++) {
            bf16x8 pa = *(const bf16x8*)&Ps[w*16 + l15][kh*32 + quad*8];
            #pragma unroll
            for (int g = 0; g < 4; g++) {
                bf16x8 vb = *(const bf16x8*)&Vs[g*16 + l15][kh*32 + quad*8];
                o[g] = __builtin_amdgcn_mfma_f32_16x16x32_bf16(pa, vb, o[g], 0, 0, 0);
            }
        }
    }
    int b_ = bh >> 3, h = bh & 7;
    #pragma unroll
    for (int g = 0; g < 4; g++) {
        #pragma unroll
        for (int r = 0; r < 4; r++) {
            int n = nrow[r];
            if (n < NN)
                attn[((size_t)(b_*NN + n))*512 + h*64 + g*16 + l15] = (bf16)o[g][r];
        }
    }
}

// ---------------- GEMM2: out = attn @ w_out + b_out ----------------
__global__ __launch_bounds__(256) void k_gemm_out(
    const bf16* __restrict__ attn, const bf16* __restrict__ wt,
    const float* __restrict__ bias, float* __restrict__ out)
{
    __shared__ bf16 As[64][LDS_STRIDE];
    __shared__ bf16 Bs[64][LDS_STRIDE];
    int t = threadIdx.x;
    int w = t >> 6, l = t & 63, l15 = l & 15, quad = l >> 4;
    int m0 = blockIdx.y * 64, c0 = blockIdx.x * 64;
    int srow = t >> 2, sseg = (t & 3) * 16;
    f32x4 acc[4] = {};

    for (int kk = 0; kk < 512; kk += 64) {
        {
            int m = m0 + srow;
            uint4 v0 = {0,0,0,0}, v1 = {0,0,0,0};
            if (m < MROWS) {
                const uint4* src = (const uint4*)(attn + (size_t)m*512 + kk + sseg);
                v0 = src[0]; v1 = src[1];
            }
            *(uint4*)&As[srow][sseg]     = v0;
            *(uint4*)&As[srow][sseg + 8] = v1;
            const uint4* bs = (const uint4*)(wt + (size_t)(c0 + srow)*512 + kk + sseg);
            *(uint4*)&Bs[srow][sseg]     = bs[0];
            *(uint4*)&Bs[srow][sseg + 8] = bs[1];
        }
        __syncthreads();
        #pragma unroll
        for (int kh = 0; kh < 2; kh++) {
            bf16x8 a = *(const bf16x8*)&As[w*16 + l15][kh*32 + quad*8];
            #pragma unroll
            for (int c = 0; c < 4; c++) {
                bf16x8 b = *(const bf16x8*)&Bs[c*16 + l15][kh*32 + quad*8];
                acc[c] = __builtin_amdgcn_mfma_f32_16x16x32_bf16(a, b, acc[c], 0, 0, 0);
            }
        }
        __syncthreads();
    }
    #pragma unroll
    for (int c = 0; c < 4; c++) {
        int col = c0 + c*16 + l15;
        float bv = bias[col];
        #pragma unroll
        for (int r = 0; r < 4; r++) {
            int m = m0 + w*16 + quad*4 + r;
            if (m < MROWS)
                out[(size_t)m*512 + col] = acc[c][r] + bv;
        }
    }
}

// ---------------- launch ----------------
extern "C" void kernel_launch(void* const* d_in, const int* in_sizes, int n_in,
                              void* d_out, int out_size, void* d_ws, size_t ws_size,
                              hipStream_t stream)
{
    const float* x     = (const float*)d_in[0];
    const float* w_qkv = (const float*)d_in[1];
    const float* b_qkv = (const float*)d_in[2];
    const float* w_out = (const float*)d_in[3];
    const float* b_out = (const float*)d_in[4];

    float* out  = (float*)d_out;
    float* A    = out + (size_t)MROWS * 512;            // 2,114,560
    float* Araw = A   + (size_t)BB * HH * NN * NN;      // +68,227,600

    char* ws = (char*)d_ws;
    size_t off = 0;
    auto alloc = [&](size_t bytes) {
        char* p = ws + off;
        off += (bytes + 255) & ~(size_t)255;
        return p;
    };
    bf16*  xb    = (bf16*)alloc((size_t)MROWS * 512 * 2);
    bf16*  wqt   = (bf16*)alloc((size_t)1536 * 512 * 2);
    bf16*  wot   = (bf16*)alloc((size_t)512 * 512 * 2);
    bf16*  Qh    = (bf16*)alloc((size_t)16 * NPAD * 64 * 2);   // contiguous with
    bf16*  Kh    = (bf16*)alloc((size_t)16 * NPAD * 64 * 2);   // Kh, Vt (sizes are
    bf16*  Vt    = (bf16*)alloc((size_t)16 * NPAD * 64 * 2);   // multiples of 256)
    float4* stats = (float4*)alloc((size_t)16 * NPAD * 16);
    bf16*  attn  = (bf16*)alloc((size_t)MROWS * 512 * 2);
    (void)ws_size; (void)in_sizes; (void)n_in; (void)out_size;

    // zero the padded Q/K/V region (3 contiguous arrays)
    int zero4 = (int)((size_t)3 * 16 * NPAD * 64 * 2 / 16);    // 811,008 uint4
    k_zero<<<dim3((zero4 + 255) / 256), 256, 0, stream>>>((uint4*)Qh, zero4);

    k_cvt<<<dim3((MROWS*512/4 + 255) / 256), 256, 0, stream>>>(x, xb, MROWS*512/4);
    k_transcvt<<<dim3(1536*512/256), 256, 0, stream>>>(w_qkv, wqt, 1536, 1536*512);
    k_transcvt<<<dim3(512*512/256),  256, 0, stream>>>(w_out, wot, 512,  512*512);

    k_gemm_qkv<<<dim3(24, 65), 256, 0, stream>>>(xb, wqt, b_qkv, Qh, Kh, Vt);
    k_attn1<<<dim3(33, 16), 256, 0, stream>>>(Qh, Kh, Araw, stats);
    k_attn2<<<dim3(33, 16), 256, 0, stream>>>(Qh, Kh, Vt, stats, A, attn);
    k_gemm_out<<<dim3(8, 65), 256, 0, stream>>>(attn, wot, b_out, out);
}